// Round 1
// baseline (47.391 us; speedup 1.0000x reference)
//
#include <hip/hip_runtime.h>

#define B 4
#define L 200
#define N 160
#define HS 768
#define HD 256
#define C 16

// ---------------------------------------------------------------------------
// Kernel 1: pooled[b,n,:] = (sum_{l in [lo,hi), l<len} TO[b,l+1,:]) @ Wd / cnt + bd
// word_mapback is sorted per batch, so the l-range for word n is contiguous:
// binary search (deterministic, no atomics). 4 word-rows per block to reuse Wd.
// ---------------------------------------------------------------------------
__global__ __launch_bounds__(256) void pool_gemm_kernel(
    const float* __restrict__ TO,    // [B, L+1, HS]
    const float* __restrict__ Wd,    // [HS, HD]
    const float* __restrict__ bd,    // [HD]
    const int*   __restrict__ wm,    // [B, L]
    const int*   __restrict__ lengths, // [B]
    float* __restrict__ pooled)      // [B, N, HD]
{
    const int b  = blockIdx.x;
    const int n0 = blockIdx.y * 4;
    const int t  = threadIdx.x;
    const int len = lengths[b];
    const int* map = wm + b * L;

    __shared__ float lds[4 * HS];   // 12 KiB

    int cnt[4];
    #pragma unroll
    for (int r = 0; r < 4; ++r) {
        const int n = n0 + r;
        // lower_bound(n) and lower_bound(n+1) over the sorted 200-entry row
        int lo = 0, hi = L;
        while (lo < hi) { int mid = (lo + hi) >> 1; if (map[mid] < n) lo = mid + 1; else hi = mid; }
        int lo2 = lo, hi2 = L;
        while (lo2 < hi2) { int mid = (lo2 + hi2) >> 1; if (map[mid] < n + 1) lo2 = mid + 1; else hi2 = mid; }
        int start = lo < len ? lo : len;
        int stop  = lo2 < len ? lo2 : len;
        cnt[r] = stop - start;

        float a0 = 0.f, a1 = 0.f, a2 = 0.f;
        const float* base = TO + ((size_t)b * (L + 1) + 1) * HS;
        for (int l = start; l < stop; ++l) {
            const float* row = base + (size_t)l * HS;
            a0 += row[t];
            a1 += row[t + 256];
            a2 += row[t + 512];
        }
        lds[r * HS + t]       = a0;
        lds[r * HS + t + 256] = a1;
        lds[r * HS + t + 512] = a2;
    }
    __syncthreads();

    float acc0 = 0.f, acc1 = 0.f, acc2 = 0.f, acc3 = 0.f;
    for (int k = 0; k < HS; ++k) {
        const float w = Wd[(size_t)k * HD + t];   // coalesced; L2-resident
        acc0 += lds[k] * w;                        // LDS broadcast reads
        acc1 += lds[HS + k] * w;
        acc2 += lds[2 * HS + k] * w;
        acc3 += lds[3 * HS + k] * w;
    }
    const float bdv = bd[t];
    float accs[4] = {acc0, acc1, acc2, acc3};
    #pragma unroll
    for (int r = 0; r < 4; ++r) {
        const float v = (cnt[r] > 0) ? (accs[r] / (float)cnt[r] + bdv) : 0.f;
        pooled[((size_t)(b * N + n0 + r)) * HD + t] = v;
    }
}

// ---------------------------------------------------------------------------
// Kernel 2: project pooled row through the three HD-blocks of Wc:
//   A[b,n,c]  = pooled[b,n,:] . Wc[0:HD, c]
//   Bm[b,n,c] = pooled[b,n,:] . Wc[HD:2HD, c]
//   T[b,n,c]  = tok_mask[b,n] * pooled[b,n,:] . Wc[2HD:3HD, c]
// One wave per (b,n); 48 of 64 lanes each own one (block m, class c) output.
// ---------------------------------------------------------------------------
__global__ __launch_bounds__(64) void project_kernel(
    const float* __restrict__ pooled,   // [B, N, HD]
    const float* __restrict__ Wc,       // [3*HD, C]
    const int*   __restrict__ token_length,
    float* __restrict__ Aout,           // [B, N, C]
    float* __restrict__ Bout,
    float* __restrict__ Tout)
{
    const int b = blockIdx.x;
    const int n = blockIdx.y;
    const int t = threadIdx.x;

    __shared__ float row[HD];
    const float* prow = pooled + (size_t)(b * N + n) * HD;
    #pragma unroll
    for (int j = 0; j < HD / 64; ++j) row[t + j * 64] = prow[t + j * 64];
    __syncthreads();

    if (t < 48) {
        const int m = t >> 4;
        const int c = t & 15;
        const float* w = Wc + (size_t)m * HD * C + c;
        float acc = 0.f;
        #pragma unroll 8
        for (int k = 0; k < HD; ++k) acc += row[k] * w[(size_t)k * C];
        const size_t o = (size_t)(b * N + n) * C + c;
        if (m == 0)      Aout[o] = acc;
        else if (m == 1) Bout[o] = acc;
        else             Tout[o] = (n < token_length[b]) ? acc : 0.f;
    }
}

// ---------------------------------------------------------------------------
// Kernel 3: S[b,n,c] = cumsum over n of T[b,n,c]  (Hillis-Steele in LDS)
// ---------------------------------------------------------------------------
__global__ __launch_bounds__(256) void scan_kernel(
    const float* __restrict__ Tout,   // [B, N, C]
    float* __restrict__ Sout)         // [B, N, C]
{
    const int b = blockIdx.x;
    const int t = threadIdx.x;
    __shared__ float buf0[N * C];
    __shared__ float buf1[N * C];

    for (int e = t; e < N * C; e += 256) buf0[e] = Tout[(size_t)b * N * C + e];
    __syncthreads();

    float* cur = buf0;
    float* nxt = buf1;
    for (int off = 1; off < N; off <<= 1) {
        for (int e = t; e < N * C; e += 256) {
            const int n = e >> 4;
            float v = cur[e];
            if (n >= off) v += cur[e - off * C];
            nxt[e] = v;
        }
        __syncthreads();
        float* tmp = cur; cur = nxt; nxt = tmp;
    }
    for (int e = t; e < N * C; e += 256) Sout[(size_t)b * N * C + e] = cur[e];
}

// ---------------------------------------------------------------------------
// Kernel 4: logits[b,i,k,c] = cand ? A[b,i,c] + Bm[b,k,c]
//                                   + (S[b,k,c] - S[b,i-1,c])/(k-i+1) + bc[c]
//                                  : 0
// ---------------------------------------------------------------------------
__global__ __launch_bounds__(256) void finalize_kernel(
    const float* __restrict__ Aout,
    const float* __restrict__ Bout,
    const float* __restrict__ Sout,
    const float* __restrict__ bc,
    const int*   __restrict__ token_length,
    float* __restrict__ out)          // [B, N, N, C]
{
    const int idx = blockIdx.x * 256 + threadIdx.x;
    const int c     = idx & (C - 1);
    const int rest  = idx >> 4;        // (b*N + i)*N + k
    const int k     = rest % N;
    const int rest2 = rest / N;
    const int i     = rest2 % N;
    const int b     = rest2 / N;

    const int tl = token_length[b];
    const bool cand = (i <= k) & (i < tl) & (k < tl);

    float v = 0.f;
    if (cand) {
        const float a  = Aout[(size_t)(b * N + i) * C + c];
        const float bb = Bout[(size_t)(b * N + k) * C + c];
        const float sk = Sout[(size_t)(b * N + k) * C + c];
        const float si = (i > 0) ? Sout[(size_t)(b * N + i - 1) * C + c] : 0.f;
        v = a + bb + (sk - si) / (float)(k - i + 1) + bc[c];
    }
    out[idx] = v;
}

extern "C" void kernel_launch(void* const* d_in, const int* in_sizes, int n_in,
                              void* d_out, int out_size, void* d_ws, size_t ws_size,
                              hipStream_t stream) {
    const float* TO   = (const float*)d_in[0];   // transformer_out [B, L+1, HS]
    const float* Wd   = (const float*)d_in[1];   // [HS, HD]
    const float* bd   = (const float*)d_in[2];   // [HD]
    const float* Wc   = (const float*)d_in[3];   // [3*HD, C]
    const float* bc   = (const float*)d_in[4];   // [C]
    const int*   wm   = (const int*)d_in[5];     // [B, L]
    const int*   tokl = (const int*)d_in[6];     // [B]
    const int*   len  = (const int*)d_in[7];     // [B]
    float* out = (float*)d_out;

    float* ws     = (float*)d_ws;
    float* pooled = ws;                       // B*N*HD = 163840 f32
    float* Aout   = pooled + B * N * HD;      // B*N*C  = 10240 f32
    float* Bout   = Aout + B * N * C;
    float* Tout   = Bout + B * N * C;
    float* Sout   = Tout + B * N * C;
    // total ws use: 819,200 bytes; every element written before read.

    pool_gemm_kernel<<<dim3(B, N / 4), 256, 0, stream>>>(TO, Wd, bd, wm, len, pooled);
    project_kernel<<<dim3(B, N), 64, 0, stream>>>(pooled, Wc, tokl, Aout, Bout, Tout);
    scan_kernel<<<B, 256, 0, stream>>>(Tout, Sout);
    finalize_kernel<<<(B * N * N * C) / 256, 256, 0, stream>>>(Aout, Bout, Sout, bc, tokl, out);
}

// Round 2
// 41.070 us; speedup vs baseline: 1.1539x; 1.1539x over previous
//
#include <hip/hip_runtime.h>

#define B 4
#define L 200
#define N 160
#define HS 768
#define HD 256
#define C 16

#define KS 8                 // split-k slices
#define KCH (HS / KS)        // 96 k per slice
#define ROWS 8               // (b,n) rows per gemm block
#define NROW (B * N)         // 640 flat rows

// ---------------------------------------------------------------------------
// Kernel 1: hsum[b,n,:] = sum_{l in [lb(n),lb(n+1)) ∩ [0,len)} TO[b,l+1,:]
//           cntinv[b,n] = cnt ? 1/cnt : 0
// word_mapback sorted per batch -> contiguous l-range via binary search.
// ---------------------------------------------------------------------------
__global__ __launch_bounds__(256) void pool_sum_kernel(
    const float* __restrict__ TO,      // [B, L+1, HS]
    const int*   __restrict__ wm,      // [B, L]
    const int*   __restrict__ lengths, // [B]
    float* __restrict__ hsum,          // [NROW, HS]
    float* __restrict__ cntinv)        // [NROW]
{
    const int b = blockIdx.x, n = blockIdx.y, t = threadIdx.x;
    const int len = lengths[b];
    const int* map = wm + b * L;

    int lo = 0, hi = L;
    while (lo < hi) { int m = (lo + hi) >> 1; if (map[m] < n) lo = m + 1; else hi = m; }
    int lo2 = lo, hi2 = L;
    while (lo2 < hi2) { int m = (lo2 + hi2) >> 1; if (map[m] < n + 1) lo2 = m + 1; else hi2 = m; }
    const int start = lo < len ? lo : len;
    const int stop  = lo2 < len ? lo2 : len;
    const int cnt   = stop - start;

    float a0 = 0.f, a1 = 0.f, a2 = 0.f;
    const float* base = TO + ((size_t)b * (L + 1) + 1) * HS;
    for (int l = start; l < stop; ++l) {
        const float* row = base + (size_t)l * HS;
        a0 += row[t]; a1 += row[t + 256]; a2 += row[t + 512];
    }
    float* hr = hsum + (size_t)(b * N + n) * HS;
    hr[t] = a0; hr[t + 256] = a1; hr[t + 512] = a2;
    if (t == 0) cntinv[b * N + n] = (cnt > 0) ? 1.0f / (float)cnt : 0.0f;
}

// ---------------------------------------------------------------------------
// Kernel 2: split-k GEMM  partial[ks, row, d] = sum_{k in slice} hsum[row,k]*Wd[k,d]
// hsum index is wave-uniform -> scalar loads (SMEM pipe), Wd per-lane coalesced.
// No LDS in the inner loop (the R0 bottleneck was LDS broadcast throughput).
// ---------------------------------------------------------------------------
__global__ __launch_bounds__(256) void gemm_partial_kernel(
    const float* __restrict__ hsum,    // [NROW, HS]
    const float* __restrict__ Wd,      // [HS, HD]
    float* __restrict__ partial)       // [KS, NROW, HD]
{
    const int ks = blockIdx.x;         // 0..KS-1
    const int rg = blockIdx.y;         // 0..NROW/ROWS-1
    const int t  = threadIdx.x;        // d
    const int k0 = ks * KCH;
    const int r0 = rg * ROWS;

    float acc[ROWS] = {};
    const float* wd = Wd + (size_t)k0 * HD + t;
    const float* hs = hsum + (size_t)r0 * HS + k0;

    #pragma unroll 8
    for (int k = 0; k < KCH; ++k) {
        const float w = wd[(size_t)k * HD];
        #pragma unroll
        for (int r = 0; r < ROWS; ++r)
            acc[r] += hs[(size_t)r * HS + k] * w;   // uniform -> s_load
    }
    #pragma unroll
    for (int r = 0; r < ROWS; ++r)
        partial[((size_t)ks * NROW + r0 + r) * HD + t] = acc[r];
}

// ---------------------------------------------------------------------------
// Kernel 3: reduce split-k partials -> pooled row (in LDS only), then project:
//   A[b,n,c]  = row . Wc[0:HD, c]
//   Bm[b,n,c] = row . Wc[HD:2HD, c]
//   T[b,n,c]  = (n < token_length[b]) ? row . Wc[2HD:3HD, c] : 0
// ---------------------------------------------------------------------------
__global__ __launch_bounds__(64) void project_kernel(
    const float* __restrict__ partial,  // [KS, NROW, HD]
    const float* __restrict__ cntinv,   // [NROW]
    const float* __restrict__ bd,       // [HD]
    const float* __restrict__ Wc,       // [3*HD, C]
    const int*   __restrict__ token_length,
    float* __restrict__ Aout,           // [NROW, C]
    float* __restrict__ Bout,
    float* __restrict__ Tout)
{
    const int b = blockIdx.x, n = blockIdx.y, t = threadIdx.x;
    const int flat = b * N + n;

    __shared__ float row[HD];
    const float ci = cntinv[flat];
    #pragma unroll
    for (int j = 0; j < HD / 64; ++j) {
        const int d = t + j * 64;
        float s = 0.f;
        #pragma unroll
        for (int ks = 0; ks < KS; ++ks)
            s += partial[((size_t)ks * NROW + flat) * HD + d];
        row[d] = (ci > 0.f) ? s * ci + bd[d] : 0.f;
    }
    __syncthreads();

    if (t < 48) {
        const int m = t >> 4;
        const int c = t & 15;
        const float* w = Wc + (size_t)m * HD * C + c;
        float acc = 0.f;
        #pragma unroll 8
        for (int k = 0; k < HD; ++k) acc += row[k] * w[(size_t)k * C];
        const size_t o = (size_t)flat * C + c;
        if (m == 0)      Aout[o] = acc;
        else if (m == 1) Bout[o] = acc;
        else             Tout[o] = (n < token_length[b]) ? acc : 0.f;
    }
}

// ---------------------------------------------------------------------------
// Kernel 4: S[b,n,c] = cumsum over n of T[b,n,c]  (Hillis-Steele in LDS)
// ---------------------------------------------------------------------------
__global__ __launch_bounds__(256) void scan_kernel(
    const float* __restrict__ Tout,   // [B, N, C]
    float* __restrict__ Sout)         // [B, N, C]
{
    const int b = blockIdx.x;
    const int t = threadIdx.x;
    __shared__ float buf0[N * C];
    __shared__ float buf1[N * C];

    for (int e = t; e < N * C; e += 256) buf0[e] = Tout[(size_t)b * N * C + e];
    __syncthreads();

    float* cur = buf0;
    float* nxt = buf1;
    for (int off = 1; off < N; off <<= 1) {
        for (int e = t; e < N * C; e += 256) {
            const int n = e >> 4;
            float v = cur[e];
            if (n >= off) v += cur[e - off * C];
            nxt[e] = v;
        }
        __syncthreads();
        float* tmp = cur; cur = nxt; nxt = tmp;
    }
    for (int e = t; e < N * C; e += 256) Sout[(size_t)b * N * C + e] = cur[e];
}

// ---------------------------------------------------------------------------
// Kernel 5: logits[b,i,k,c] = cand ? A[i] + Bm[k] + (S[k]-S[i-1])/(k-i+1) + bc : 0
// float4 over c (C=16 -> 4 quads); one reciprocal per thread.
// ---------------------------------------------------------------------------
__global__ __launch_bounds__(256) void finalize_kernel(
    const float* __restrict__ Aout,
    const float* __restrict__ Bout,
    const float* __restrict__ Sout,
    const float* __restrict__ bc,
    const int*   __restrict__ token_length,
    float4* __restrict__ out)          // [B*N*N*C/4]
{
    const int idx = blockIdx.x * 256 + threadIdx.x;   // quad index
    const int q     = idx & 3;          // c-quad
    const int rest  = idx >> 2;         // (b*N + i)*N + k
    const int k     = rest % N;
    const int rest2 = rest / N;
    const int i     = rest2 % N;
    const int b     = rest2 / N;

    const int tl = token_length[b];
    const bool cand = (i <= k) & (i < tl) & (k < tl);

    float4 v = {0.f, 0.f, 0.f, 0.f};
    if (cand) {
        const int co = q * 4;
        const float4 a  = *(const float4*)&Aout[(size_t)(b * N + i) * C + co];
        const float4 bb = *(const float4*)&Bout[(size_t)(b * N + k) * C + co];
        const float4 sk = *(const float4*)&Sout[(size_t)(b * N + k) * C + co];
        float4 si = {0.f, 0.f, 0.f, 0.f};
        if (i > 0) si = *(const float4*)&Sout[(size_t)(b * N + i - 1) * C + co];
        const float4 bcv = *(const float4*)&bc[co];
        const float inv = 1.0f / (float)(k - i + 1);
        v.x = a.x + bb.x + (sk.x - si.x) * inv + bcv.x;
        v.y = a.y + bb.y + (sk.y - si.y) * inv + bcv.y;
        v.z = a.z + bb.z + (sk.z - si.z) * inv + bcv.z;
        v.w = a.w + bb.w + (sk.w - si.w) * inv + bcv.w;
    }
    out[idx] = v;
}

extern "C" void kernel_launch(void* const* d_in, const int* in_sizes, int n_in,
                              void* d_out, int out_size, void* d_ws, size_t ws_size,
                              hipStream_t stream) {
    const float* TO   = (const float*)d_in[0];   // transformer_out [B, L+1, HS]
    const float* Wd   = (const float*)d_in[1];   // [HS, HD]
    const float* bd   = (const float*)d_in[2];   // [HD]
    const float* Wc   = (const float*)d_in[3];   // [3*HD, C]
    const float* bc   = (const float*)d_in[4];   // [C]
    const int*   wm   = (const int*)d_in[5];     // [B, L]
    const int*   tokl = (const int*)d_in[6];     // [B]
    const int*   len  = (const int*)d_in[7];     // [B]

    float* ws      = (float*)d_ws;
    float* hsum    = ws;                          // NROW*HS   = 491520 f32
    float* cntinv  = hsum + (size_t)NROW * HS;    // NROW      = 640
    float* partial = cntinv + NROW;               // KS*NROW*HD = 1310720 f32
    float* Aout    = partial + (size_t)KS * NROW * HD;  // NROW*C = 10240
    float* Bout    = Aout + NROW * C;
    float* Tout    = Bout + NROW * C;
    float* Sout    = Tout + NROW * C;
    // total ws use ~7.4 MB; every element written before read each call.

    pool_sum_kernel<<<dim3(B, N), 256, 0, stream>>>(TO, wm, len, hsum, cntinv);
    gemm_partial_kernel<<<dim3(KS, NROW / ROWS), 256, 0, stream>>>(hsum, Wd, partial);
    project_kernel<<<dim3(B, N), 64, 0, stream>>>(partial, cntinv, bd, Wc, tokl, Aout, Bout, Tout);
    scan_kernel<<<B, 256, 0, stream>>>(Tout, Sout);
    finalize_kernel<<<(B * N * N * C / 4) / 256, 256, 0, stream>>>(Aout, Bout, Sout, bc, tokl, (float4*)d_out);
}